// Round 1
// baseline (158.711 us; speedup 1.0000x reference)
//
#include <hip/hip_runtime.h>

// DiscriminatorIndependent: 1024 tiny MLPs (2->4->1, relu), B=16384,
// out[b] = mean_n ( W2[n] . relu(W1[n] @ [x[b,n], xa[b,n]] + b1[n]) + b2[n] )
//
// Memory-bound: 128 MiB payload (x, x_aug) dominates. Strategy:
//  - block = 256 threads, each thread owns 4 consecutive MLPs (n = 4t..4t+3),
//    keeps all 17 params/MLP in registers (loaded once per block).
//  - block processes ROWS=16 batch rows, reusing the in-register params.
//  - payload loads are float4, fully coalesced (4 KB contiguous per row/block).
//  - per-row reduction: wave shuffle tree + tiny LDS combine.

constexpr int N_MLP = 1024;
constexpr int BATCH = 16384;
constexpr int ROWS = 16;      // batch rows per block
constexpr int NTHREADS = 256; // 4 waves

__global__ __launch_bounds__(NTHREADS)
void disc_mlp_kernel(const float* __restrict__ x,
                     const float* __restrict__ xa,
                     const float* __restrict__ W1,
                     const float* __restrict__ b1,
                     const float* __restrict__ W2,
                     const float* __restrict__ b2,
                     float* __restrict__ out)
{
    const int t  = threadIdx.x;
    const int b0 = blockIdx.x * ROWS;
    const int n0 = t * 4;   // 4 consecutive MLPs per thread

    // ---- load per-MLP params into registers (once per block) ----
    // W1 layout per n: [j0e0, j0e1, j1e0, j1e1, j2e0, j2e1, j3e0, j3e1]
    float A[4][4];   // A[nn][j] = W1[n0+nn][j][0]
    float C[4][4];   // C[nn][j] = W1[n0+nn][j][1]
    float B1[4][4];  // b1
    float V[4][4];   // W2 row
    float b2sum = 0.0f;
    {
        const float4* w1v = reinterpret_cast<const float4*>(W1) + (size_t)n0 * 2;
        const float4* b1v = reinterpret_cast<const float4*>(b1) + n0;
        const float4* w2v = reinterpret_cast<const float4*>(W2) + n0;
#pragma unroll
        for (int nn = 0; nn < 4; ++nn) {
            float4 p0 = w1v[nn * 2];
            float4 p1 = w1v[nn * 2 + 1];
            A[nn][0] = p0.x; C[nn][0] = p0.y;
            A[nn][1] = p0.z; C[nn][1] = p0.w;
            A[nn][2] = p1.x; C[nn][2] = p1.y;
            A[nn][3] = p1.z; C[nn][3] = p1.w;
            float4 bb = b1v[nn];
            B1[nn][0] = bb.x; B1[nn][1] = bb.y; B1[nn][2] = bb.z; B1[nn][3] = bb.w;
            float4 ww = w2v[nn];
            V[nn][0] = ww.x; V[nn][1] = ww.y; V[nn][2] = ww.z; V[nn][3] = ww.w;
            b2sum += b2[n0 + nn];
        }
    }

    // ---- main loop over ROWS batch rows ----
    float acc[ROWS];
#pragma unroll
    for (int r = 0; r < ROWS; ++r) acc[r] = 0.0f;

    const size_t rowbase = (size_t)b0 * N_MLP + n0;
#pragma unroll 4
    for (int r = 0; r < ROWS; ++r) {
        const float4 xv  = *reinterpret_cast<const float4*>(x  + rowbase + (size_t)r * N_MLP);
        const float4 xav = *reinterpret_cast<const float4*>(xa + rowbase + (size_t)r * N_MLP);
        const float xe[4]  = {xv.x,  xv.y,  xv.z,  xv.w};
        const float xae[4] = {xav.x, xav.y, xav.z, xav.w};
        float s = b2sum;
#pragma unroll
        for (int nn = 0; nn < 4; ++nn) {
#pragma unroll
            for (int j = 0; j < 4; ++j) {
                float h = fmaf(A[nn][j], xe[nn], fmaf(C[nn][j], xae[nn], B1[nn][j]));
                h = fmaxf(h, 0.0f);
                s = fmaf(V[nn][j], h, s);
            }
        }
        acc[r] = s;
    }

    // ---- per-row reduction: wave shuffle tree then LDS combine ----
    __shared__ float lds[NTHREADS / 64][ROWS];
    const int lane = t & 63;
    const int wave = t >> 6;
#pragma unroll
    for (int r = 0; r < ROWS; ++r) {
        float v = acc[r];
        v += __shfl_down(v, 32);
        v += __shfl_down(v, 16);
        v += __shfl_down(v, 8);
        v += __shfl_down(v, 4);
        v += __shfl_down(v, 2);
        v += __shfl_down(v, 1);
        if (lane == 0) lds[wave][r] = v;
    }
    __syncthreads();
    if (t < ROWS) {
        float s = lds[0][t] + lds[1][t] + lds[2][t] + lds[3][t];
        out[b0 + t] = s * (1.0f / (float)N_MLP);
    }
}

extern "C" void kernel_launch(void* const* d_in, const int* in_sizes, int n_in,
                              void* d_out, int out_size, void* d_ws, size_t ws_size,
                              hipStream_t stream) {
    const float* x  = (const float*)d_in[0];
    const float* xa = (const float*)d_in[1];
    const float* W1 = (const float*)d_in[2];
    const float* b1 = (const float*)d_in[3];
    const float* W2 = (const float*)d_in[4];
    const float* b2 = (const float*)d_in[5];
    float* out = (float*)d_out;

    disc_mlp_kernel<<<BATCH / ROWS, NTHREADS, 0, stream>>>(x, xa, W1, b1, W2, b2, out);
}

// Round 2
// 156.560 us; speedup vs baseline: 1.0137x; 1.0137x over previous
//
#include <hip/hip_runtime.h>

// DiscriminatorIndependent: 1024 tiny MLPs (2->4->1, relu), B=16384,
// out[b] = mean_n ( W2[n] . relu(W1[n] @ [x[b,n], xa[b,n]] + b1[n]) + b2[n] )
//
// Memory-bound: 128 MiB payload (x, x_aug). R1 lesson: without register
// headroom the compiler capped at 60 VGPRs and re-loaded the per-thread
// params every row chunk (latency-bound, 53 us). Fix: __launch_bounds__(256,2)
// (VGPR cap 256) + fully-unrolled row loop in chunks of 8 with all loads
// hoisted, so params (65 regs) + acc (16) + load buffers (64) stay resident.

constexpr int N_MLP = 1024;
constexpr int BATCH = 16384;
constexpr int ROWS = 16;      // batch rows per block
constexpr int CH = 8;         // rows per load/compute chunk
constexpr int NTHREADS = 256; // 4 waves

__global__ __launch_bounds__(NTHREADS, 2)
void disc_mlp_kernel(const float* __restrict__ x,
                     const float* __restrict__ xa,
                     const float* __restrict__ W1,
                     const float* __restrict__ b1,
                     const float* __restrict__ W2,
                     const float* __restrict__ b2,
                     float* __restrict__ out)
{
    const int t  = threadIdx.x;
    const int b0 = blockIdx.x * ROWS;
    const int n0 = t * 4;   // 4 consecutive MLPs per thread

    // ---- per-MLP params -> registers (once per block) ----
    // W1 layout per n: [j0e0, j0e1, j1e0, j1e1, j2e0, j2e1, j3e0, j3e1]
    float A[4][4];   // A[nn][j] = W1[n0+nn][j][0]
    float C[4][4];   // C[nn][j] = W1[n0+nn][j][1]
    float B1[4][4];  // b1
    float V[4][4];   // W2 row
    float b2sum;
    {
        const float4* w1v = reinterpret_cast<const float4*>(W1) + (size_t)n0 * 2;
        const float4* b1v = reinterpret_cast<const float4*>(b1) + n0;
        const float4* w2v = reinterpret_cast<const float4*>(W2) + n0;
        float4 p[8], bb[4], ww[4];
#pragma unroll
        for (int nn = 0; nn < 4; ++nn) {
            p[2 * nn]     = w1v[nn * 2];
            p[2 * nn + 1] = w1v[nn * 2 + 1];
            bb[nn] = b1v[nn];
            ww[nn] = w2v[nn];
        }
        float4 b2q = *(reinterpret_cast<const float4*>(b2) + t);
        b2sum = (b2q.x + b2q.y) + (b2q.z + b2q.w);
#pragma unroll
        for (int nn = 0; nn < 4; ++nn) {
            A[nn][0] = p[2*nn].x;   C[nn][0] = p[2*nn].y;
            A[nn][1] = p[2*nn].z;   C[nn][1] = p[2*nn].w;
            A[nn][2] = p[2*nn+1].x; C[nn][2] = p[2*nn+1].y;
            A[nn][3] = p[2*nn+1].z; C[nn][3] = p[2*nn+1].w;
            B1[nn][0] = bb[nn].x; B1[nn][1] = bb[nn].y;
            B1[nn][2] = bb[nn].z; B1[nn][3] = bb[nn].w;
            V[nn][0] = ww[nn].x; V[nn][1] = ww[nn].y;
            V[nn][2] = ww[nn].z; V[nn][3] = ww[nn].w;
        }
    }

    float acc[ROWS];
    const size_t rowbase = (size_t)b0 * N_MLP + n0;

#pragma unroll
    for (int rc = 0; rc < ROWS; rc += CH) {
        // hoist all loads for this chunk (16 float4s in flight)
        float4 xv[CH], xav[CH];
#pragma unroll
        for (int i = 0; i < CH; ++i) {
            xv[i]  = *reinterpret_cast<const float4*>(x  + rowbase + (size_t)(rc + i) * N_MLP);
            xav[i] = *reinterpret_cast<const float4*>(xa + rowbase + (size_t)(rc + i) * N_MLP);
        }
#pragma unroll
        for (int i = 0; i < CH; ++i) {
            const float xe[4]  = {xv[i].x,  xv[i].y,  xv[i].z,  xv[i].w};
            const float xae[4] = {xav[i].x, xav[i].y, xav[i].z, xav[i].w};
            float s = b2sum;
#pragma unroll
            for (int nn = 0; nn < 4; ++nn) {
#pragma unroll
                for (int j = 0; j < 4; ++j) {
                    float h = fmaf(A[nn][j], xe[nn], fmaf(C[nn][j], xae[nn], B1[nn][j]));
                    h = fmaxf(h, 0.0f);
                    s = fmaf(V[nn][j], h, s);
                }
            }
            acc[rc + i] = s;
        }
    }

    // ---- per-row reduction: wave shuffle tree then LDS combine ----
    __shared__ float lds[NTHREADS / 64][ROWS];
    const int lane = t & 63;
    const int wave = t >> 6;
#pragma unroll
    for (int r = 0; r < ROWS; ++r) {
        float v = acc[r];
        v += __shfl_down(v, 32);
        v += __shfl_down(v, 16);
        v += __shfl_down(v, 8);
        v += __shfl_down(v, 4);
        v += __shfl_down(v, 2);
        v += __shfl_down(v, 1);
        if (lane == 0) lds[wave][r] = v;
    }
    __syncthreads();
    if (t < ROWS) {
        float s = (lds[0][t] + lds[1][t]) + (lds[2][t] + lds[3][t]);
        out[b0 + t] = s * (1.0f / (float)N_MLP);
    }
}

extern "C" void kernel_launch(void* const* d_in, const int* in_sizes, int n_in,
                              void* d_out, int out_size, void* d_ws, size_t ws_size,
                              hipStream_t stream) {
    const float* x  = (const float*)d_in[0];
    const float* xa = (const float*)d_in[1];
    const float* W1 = (const float*)d_in[2];
    const float* b1 = (const float*)d_in[3];
    const float* W2 = (const float*)d_in[4];
    const float* b2 = (const float*)d_in[5];
    float* out = (float*)d_out;

    disc_mlp_kernel<<<BATCH / ROWS, NTHREADS, 0, stream>>>(x, xa, W1, b1, W2, b2, out);
}

// Round 3
// 150.882 us; speedup vs baseline: 1.0519x; 1.0376x over previous
//
#include <hip/hip_runtime.h>

// DiscriminatorIndependent: 1024 tiny MLPs (2->4->1, relu), B=16384,
// out[b] = mean_n ( W2[n] . relu(W1[n] @ [x[b,n], xa[b,n]] + b1[n]) + b2[n] )
//
// R1/R2 lesson: 4 MLPs/thread needs ~130 live VGPRs -> compiler spills to
// scratch; scratch is L2-contained (invisible in FETCH/WRITE) and makes the
// kernel latency-bound at ~50 us regardless of cache state.
// R3: 1 MLP/thread (17 param regs). Block = 256 threads = one 256-MLP quarter
// of N, covering 16 batch rows. 4 quarter-blocks combine per row via
// atomicAdd into zero-filled out. ~60 VGPRs -> no spills; 4096 blocks -> TLP.

constexpr int N_MLP = 1024;
constexpr int BATCH = 16384;
constexpr int ROWS = 16;      // batch rows per block
constexpr int CH = 8;         // rows per hoisted load chunk
constexpr int NTHREADS = 256; // 4 waves; covers 256 MLPs
constexpr int NQ = N_MLP / NTHREADS; // 4 n-quarters

__global__ __launch_bounds__(256)
void zero_out_kernel(float* __restrict__ out) {
    out[blockIdx.x * 256 + threadIdx.x] = 0.0f;
}

__global__ __launch_bounds__(NTHREADS)
void disc_mlp_kernel(const float* __restrict__ x,
                     const float* __restrict__ xa,
                     const float* __restrict__ W1,
                     const float* __restrict__ b1,
                     const float* __restrict__ W2,
                     const float* __restrict__ b2,
                     float* __restrict__ out)
{
    const int t  = threadIdx.x;
    const int q  = blockIdx.x & (NQ - 1);        // n-quarter
    const int rb = blockIdx.x >> 2;              // row tile
    const int b0 = rb * ROWS;
    const int n  = q * NTHREADS + t;             // this thread's MLP

    // ---- this MLP's params -> 17 registers ----
    // W1 per n: [h0e0,h0e1,h1e0,h1e1,h2e0,h2e1,h3e0,h3e1]
    float A[4], C[4], B1r[4], V[4], b2r;
    {
        const float4* w1v = reinterpret_cast<const float4*>(W1) + (size_t)n * 2;
        float4 p0 = w1v[0];
        float4 p1 = w1v[1];
        A[0] = p0.x; C[0] = p0.y;
        A[1] = p0.z; C[1] = p0.w;
        A[2] = p1.x; C[2] = p1.y;
        A[3] = p1.z; C[3] = p1.w;
        float4 bb = reinterpret_cast<const float4*>(b1)[n];
        B1r[0] = bb.x; B1r[1] = bb.y; B1r[2] = bb.z; B1r[3] = bb.w;
        float4 ww = reinterpret_cast<const float4*>(W2)[n];
        V[0] = ww.x; V[1] = ww.y; V[2] = ww.z; V[3] = ww.w;
        b2r = b2[n];
    }

    float acc[ROWS];
    const size_t base = (size_t)b0 * N_MLP + n;

#pragma unroll
    for (int rc = 0; rc < ROWS; rc += CH) {
        float xe[CH], xae[CH];
#pragma unroll
        for (int i = 0; i < CH; ++i) {
            xe[i]  = x [base + (size_t)(rc + i) * N_MLP];
            xae[i] = xa[base + (size_t)(rc + i) * N_MLP];
        }
#pragma unroll
        for (int i = 0; i < CH; ++i) {
            float s = b2r;
#pragma unroll
            for (int j = 0; j < 4; ++j) {
                float h = fmaf(A[j], xe[i], fmaf(C[j], xae[i], B1r[j]));
                h = fmaxf(h, 0.0f);
                s = fmaf(V[j], h, s);
            }
            acc[rc + i] = s;
        }
    }

    // ---- reduce each row across 256 threads (256 MLPs) ----
    __shared__ float lds[NTHREADS / 64][ROWS];
    const int lane = t & 63;
    const int wave = t >> 6;
#pragma unroll
    for (int r = 0; r < ROWS; ++r) {
        float v = acc[r];
        v += __shfl_down(v, 32);
        v += __shfl_down(v, 16);
        v += __shfl_down(v, 8);
        v += __shfl_down(v, 4);
        v += __shfl_down(v, 2);
        v += __shfl_down(v, 1);
        if (lane == 0) lds[wave][r] = v;
    }
    __syncthreads();
    if (t < ROWS) {
        float s = (lds[0][t] + lds[1][t]) + (lds[2][t] + lds[3][t]);
        atomicAdd(out + b0 + t, s * (1.0f / (float)N_MLP));
    }
}

extern "C" void kernel_launch(void* const* d_in, const int* in_sizes, int n_in,
                              void* d_out, int out_size, void* d_ws, size_t ws_size,
                              hipStream_t stream) {
    const float* x  = (const float*)d_in[0];
    const float* xa = (const float*)d_in[1];
    const float* W1 = (const float*)d_in[2];
    const float* b1 = (const float*)d_in[3];
    const float* W2 = (const float*)d_in[4];
    const float* b2 = (const float*)d_in[5];
    float* out = (float*)d_out;

    zero_out_kernel<<<BATCH / 256, 256, 0, stream>>>(out);
    disc_mlp_kernel<<<(BATCH / ROWS) * NQ, NTHREADS, 0, stream>>>(x, xa, W1, b1, W2, b2, out);
}

// Round 4
// 150.852 us; speedup vs baseline: 1.0521x; 1.0002x over previous
//
#include <hip/hip_runtime.h>

// DiscriminatorIndependent: 1024 tiny MLPs (2->4->1, relu), B=16384,
// out[b] = mean_n ( W2[n] . relu(W1[n] @ [x[b,n], xa[b,n]] + b1[n]) + b2[n] )
//
// R3 post-mortem: wave lifetime ~30K cycles ~= 32 loads x 900-cy HBM latency
// -> loads were fully serialized (compiler rolled them, VGPR=32). Fix: one
// wave = one load batch. ROWS=8, all 16 payload loads issued as independent
// named scalars BEFORE any use; params (17 regs) + loads (16) + acc (8) ~ 51
// VGPRs; __launch_bounds__(256,6) caps at ~84 (no spill, no rolling).
// Grid = 8192 blocks -> 128 waves/CU of work to hide the single latency.

constexpr int N_MLP = 1024;
constexpr int BATCH = 16384;
constexpr int ROWS = 8;       // batch rows per block
constexpr int NTHREADS = 256; // 4 waves; covers 256 MLPs
constexpr int NQ = N_MLP / NTHREADS; // 4 n-quarters

__global__ __launch_bounds__(256)
void zero_out_kernel(float* __restrict__ out) {
    out[blockIdx.x * 256 + threadIdx.x] = 0.0f;
}

__global__ __launch_bounds__(NTHREADS, 6)
void disc_mlp_kernel(const float* __restrict__ x,
                     const float* __restrict__ xa,
                     const float* __restrict__ W1,
                     const float* __restrict__ b1,
                     const float* __restrict__ W2,
                     const float* __restrict__ b2,
                     float* __restrict__ out)
{
    const int t  = threadIdx.x;
    const int q  = blockIdx.x & (NQ - 1);        // n-quarter
    const int rb = blockIdx.x >> 2;              // row tile
    const int b0 = rb * ROWS;
    const int n  = q * NTHREADS + t;             // this thread's MLP

    // ---- this MLP's params -> 17 registers ----
    // W1 per n: [h0e0,h0e1,h1e0,h1e1,h2e0,h2e1,h3e0,h3e1]
    const float4 p0 = reinterpret_cast<const float4*>(W1)[(size_t)n * 2];
    const float4 p1 = reinterpret_cast<const float4*>(W1)[(size_t)n * 2 + 1];
    const float4 bb = reinterpret_cast<const float4*>(b1)[n];
    const float4 ww = reinterpret_cast<const float4*>(W2)[n];
    const float  b2r = b2[n];

    const size_t base = (size_t)b0 * N_MLP + n;

    // ---- issue ALL 16 payload loads back-to-back (one latency per wave) ----
    const float x0 = x[base + 0 * N_MLP];
    const float x1 = x[base + 1 * N_MLP];
    const float x2 = x[base + 2 * N_MLP];
    const float x3 = x[base + 3 * N_MLP];
    const float x4 = x[base + 4 * N_MLP];
    const float x5 = x[base + 5 * N_MLP];
    const float x6 = x[base + 6 * N_MLP];
    const float x7 = x[base + 7 * N_MLP];
    const float a0 = xa[base + 0 * N_MLP];
    const float a1 = xa[base + 1 * N_MLP];
    const float a2 = xa[base + 2 * N_MLP];
    const float a3 = xa[base + 3 * N_MLP];
    const float a4 = xa[base + 4 * N_MLP];
    const float a5 = xa[base + 5 * N_MLP];
    const float a6 = xa[base + 6 * N_MLP];
    const float a7 = xa[base + 7 * N_MLP];

    const float A[4]  = {p0.x, p0.z, p1.x, p1.z};
    const float C[4]  = {p0.y, p0.w, p1.y, p1.w};
    const float B1r[4] = {bb.x, bb.y, bb.z, bb.w};
    const float V[4]  = {ww.x, ww.y, ww.z, ww.w};

    const float xe[ROWS]  = {x0, x1, x2, x3, x4, x5, x6, x7};
    const float xae[ROWS] = {a0, a1, a2, a3, a4, a5, a6, a7};

    float acc[ROWS];
#pragma unroll
    for (int r = 0; r < ROWS; ++r) {
        float s = b2r;
#pragma unroll
        for (int j = 0; j < 4; ++j) {
            float h = fmaf(A[j], xe[r], fmaf(C[j], xae[r], B1r[j]));
            h = fmaxf(h, 0.0f);
            s = fmaf(V[j], h, s);
        }
        acc[r] = s;
    }

    // ---- reduce each row across the block's 256 threads (256 MLPs) ----
    __shared__ float lds[NTHREADS / 64][ROWS];
    const int lane = t & 63;
    const int wave = t >> 6;
#pragma unroll
    for (int r = 0; r < ROWS; ++r) {
        float v = acc[r];
        v += __shfl_down(v, 32);
        v += __shfl_down(v, 16);
        v += __shfl_down(v, 8);
        v += __shfl_down(v, 4);
        v += __shfl_down(v, 2);
        v += __shfl_down(v, 1);
        if (lane == 0) lds[wave][r] = v;
    }
    __syncthreads();
    if (t < ROWS) {
        float s = (lds[0][t] + lds[1][t]) + (lds[2][t] + lds[3][t]);
        atomicAdd(out + b0 + t, s * (1.0f / (float)N_MLP));
    }
}

extern "C" void kernel_launch(void* const* d_in, const int* in_sizes, int n_in,
                              void* d_out, int out_size, void* d_ws, size_t ws_size,
                              hipStream_t stream) {
    const float* x  = (const float*)d_in[0];
    const float* xa = (const float*)d_in[1];
    const float* W1 = (const float*)d_in[2];
    const float* b1 = (const float*)d_in[3];
    const float* W2 = (const float*)d_in[4];
    const float* b2 = (const float*)d_in[5];
    float* out = (float*)d_out;

    zero_out_kernel<<<BATCH / 256, 256, 0, stream>>>(out);
    disc_mlp_kernel<<<(BATCH / ROWS) * NQ, NTHREADS, 0, stream>>>(x, xa, W1, b1, W2, b2, out);
}

// Round 5
// 150.234 us; speedup vs baseline: 1.0564x; 1.0041x over previous
//
#include <hip/hip_runtime.h>

// DiscriminatorIndependent: 1024 tiny MLPs (2->4->1, relu), B=16384.
//
// R1-R4 lesson: every register-resident variant was latency-bound at 43-53us
// because the compiler schedules scalar payload loads serialized (~1 load in
// flight/wave -> ~2KB/CU outstanding -> 1.5 TB/s). Fix: async global->LDS
// staging via __builtin_amdgcn_global_load_lds(width=16): no VGPR dest, so
// the scheduler can't serialize it; 8 independent 1KB/wave requests in
// flight. Compute then reads from LDS (~6cy) instead of HBM (~900cy).
//
// Block = 256 threads = one 256-MLP quarter of N, ROWS=16 batch rows.
// LDS: 16 rows x 256 floats for x and xa = 32 KB. 4 quarter-blocks combine
// per row via atomicAdd into zero-filled out.

constexpr int N_MLP = 1024;
constexpr int BATCH = 16384;
constexpr int ROWS = 16;       // batch rows per block
constexpr int NTHREADS = 256;  // 4 waves; covers QN MLPs
constexpr int QN = 256;        // MLPs per block (quarter of N)
constexpr int NQ = N_MLP / QN; // 4 quarters

typedef __attribute__((address_space(3))) void lds_void;
typedef const __attribute__((address_space(1))) void gbl_void;

__global__ __launch_bounds__(256)
void zero_out_kernel(float* __restrict__ out) {
    out[blockIdx.x * 256 + threadIdx.x] = 0.0f;
}

__global__ __launch_bounds__(NTHREADS)
void disc_mlp_kernel(const float* __restrict__ x,
                     const float* __restrict__ xa,
                     const float* __restrict__ W1,
                     const float* __restrict__ b1,
                     const float* __restrict__ W2,
                     const float* __restrict__ b2,
                     float* __restrict__ out)
{
    __shared__ float xbuf[ROWS * QN];   // 16 KB
    __shared__ float abuf[ROWS * QN];   // 16 KB
    __shared__ float red[NTHREADS / 64][ROWS];

    const int t    = threadIdx.x;
    const int lane = t & 63;
    const int wave = t >> 6;
    const int q  = blockIdx.x & (NQ - 1);  // n-quarter
    const int rb = blockIdx.x >> 2;        // row tile
    const int b0 = rb * ROWS;
    const int n  = q * QN + t;             // this thread's MLP

    // ---- this MLP's params -> 17 registers (overlaps with staging) ----
    const float4 p0 = reinterpret_cast<const float4*>(W1)[(size_t)n * 2];
    const float4 p1 = reinterpret_cast<const float4*>(W1)[(size_t)n * 2 + 1];
    const float4 bb = reinterpret_cast<const float4*>(b1)[n];
    const float4 ww = reinterpret_cast<const float4*>(W2)[n];
    const float  b2r = b2[n];

    // ---- async global->LDS staging: each wave stages 4 rows of x and xa ----
    // Per (wave,row): 64 lanes x 16B = 1KB = one 256-float quarter-row.
    const float* gx = x  + (size_t)b0 * N_MLP + q * QN;
    const float* ga = xa + (size_t)b0 * N_MLP + q * QN;
#pragma unroll
    for (int i = 0; i < ROWS / 4; ++i) {
        const int r = wave * (ROWS / 4) + i;
        const float* srcx = gx + (size_t)r * N_MLP + lane * 4;
        const float* srca = ga + (size_t)r * N_MLP + lane * 4;
        __builtin_amdgcn_global_load_lds((gbl_void*)srcx,
                                         (lds_void*)&xbuf[r * QN + lane * 4],
                                         16, 0, 0);
        __builtin_amdgcn_global_load_lds((gbl_void*)srca,
                                         (lds_void*)&abuf[r * QN + lane * 4],
                                         16, 0, 0);
    }
    __syncthreads();   // drains vmcnt: all 32 KB resident

    const float A[4]   = {p0.x, p0.z, p1.x, p1.z};
    const float C[4]   = {p0.y, p0.w, p1.y, p1.w};
    const float B1r[4] = {bb.x, bb.y, bb.z, bb.w};
    const float V[4]   = {ww.x, ww.y, ww.z, ww.w};

    // ---- compute from LDS ----
    float acc[ROWS];
#pragma unroll
    for (int r = 0; r < ROWS; ++r) {
        const float xe  = xbuf[r * QN + t];
        const float xae = abuf[r * QN + t];
        float s = b2r;
#pragma unroll
        for (int j = 0; j < 4; ++j) {
            float h = fmaf(A[j], xe, fmaf(C[j], xae, B1r[j]));
            h = fmaxf(h, 0.0f);
            s = fmaf(V[j], h, s);
        }
        acc[r] = s;
    }

    // ---- reduce each row across the block's 256 threads ----
#pragma unroll
    for (int r = 0; r < ROWS; ++r) {
        float v = acc[r];
        v += __shfl_down(v, 32);
        v += __shfl_down(v, 16);
        v += __shfl_down(v, 8);
        v += __shfl_down(v, 4);
        v += __shfl_down(v, 2);
        v += __shfl_down(v, 1);
        if (lane == 0) red[wave][r] = v;
    }
    __syncthreads();
    if (t < ROWS) {
        float s = (red[0][t] + red[1][t]) + (red[2][t] + red[3][t]);
        atomicAdd(out + b0 + t, s * (1.0f / (float)N_MLP));
    }
}

extern "C" void kernel_launch(void* const* d_in, const int* in_sizes, int n_in,
                              void* d_out, int out_size, void* d_ws, size_t ws_size,
                              hipStream_t stream) {
    const float* x  = (const float*)d_in[0];
    const float* xa = (const float*)d_in[1];
    const float* W1 = (const float*)d_in[2];
    const float* b1 = (const float*)d_in[3];
    const float* W2 = (const float*)d_in[4];
    const float* b2 = (const float*)d_in[5];
    float* out = (float*)d_out;

    zero_out_kernel<<<BATCH / 256, 256, 0, stream>>>(out);
    disc_mlp_kernel<<<(BATCH / ROWS) * NQ, NTHREADS, 0, stream>>>(x, xa, W1, b1, W2, b2, out);
}